// Round 1
// baseline (2059.017 us; speedup 1.0000x reference)
//
#include <hip/hip_runtime.h>
#include <math.h>

#define B 128
#define S 2048
#define V 800
#define E 128
#define H 64
#define NL 3
#define M (B*S)

typedef unsigned short ushort_t;

__device__ __forceinline__ float bf2f(unsigned short u){
  return __uint_as_float(((unsigned int)u) << 16);
}
__device__ __forceinline__ unsigned short f2bf(float f){
  unsigned int u = __float_as_uint(f);
  u += 0x7fff + ((u >> 16) & 1);          // round-to-nearest-even
  return (unsigned short)(u >> 16);
}
__device__ __forceinline__ float bcast_lane(float v, int j){
  return __int_as_float(__builtin_amdgcn_readlane(__float_as_int(v), j));
}
__device__ __forceinline__ float fast_tanh(float x){
  float e = __expf(2.f*x);
  return 1.f - 2.f*__builtin_amdgcn_rcpf(e+1.f);
}
__device__ __forceinline__ int clamp_t(int t){
  return t < 0 ? 0 : (t > S-1 ? S-1 : t);
}

// 64-fma dot of wave-distributed h against per-lane row w[64].
// Batched readlane broadcasts to keep SGPR-write -> VALU-read distance.
#define REC_DOT(dotv) do {                                                   \
  float s0_=0.f,s1_=0.f,s2_=0.f,s3_=0.f;                                     \
  _Pragma("unroll")                                                          \
  for (int j=0;j<H;j+=8){                                                    \
    float b0_=bcast_lane(h,j+0), b1_=bcast_lane(h,j+1);                      \
    float b2_=bcast_lane(h,j+2), b3_=bcast_lane(h,j+3);                      \
    float b4_=bcast_lane(h,j+4), b5_=bcast_lane(h,j+5);                      \
    float b6_=bcast_lane(h,j+6), b7_=bcast_lane(h,j+7);                      \
    s0_ = fmaf(w[j+0], b0_, s0_);                                            \
    s1_ = fmaf(w[j+1], b1_, s1_);                                            \
    s2_ = fmaf(w[j+2], b2_, s2_);                                            \
    s3_ = fmaf(w[j+3], b3_, s3_);                                            \
    s0_ = fmaf(w[j+4], b4_, s0_);                                            \
    s1_ = fmaf(w[j+5], b5_, s1_);                                            \
    s2_ = fmaf(w[j+6], b6_, s2_);                                            \
    s3_ = fmaf(w[j+7], b7_, s3_);                                            \
  }                                                                          \
  dotv = (s0_+s1_)+(s2_+s3_);                                                \
} while(0)

// pre_emb[v][n] = emb[v]·w_ih[0,n,:] + b_ih[0,n] + b_hh[0,n],  n = d*64+i
__global__ __launch_bounds__(128) void k_pre_emb(const float* __restrict__ emb,
    const float* __restrict__ w_ih, const float* __restrict__ b_ih, const float* __restrict__ b_hh,
    float* __restrict__ pe)
{
  const int v = blockIdx.x;
  const int n = threadIdx.x;           // 0..127
  const float* er = emb + (size_t)v*E;
  const float* wr = w_ih + (size_t)n*E;   // layer 0 rows
  float acc = b_ih[n] + b_hh[n];
  #pragma unroll
  for (int e=0;e<E;e+=4){
    float4 ev = *(const float4*)(er+e);
    float4 wv = *(const float4*)(wr+e);
    acc = fmaf(ev.x, wv.x, acc);
    acc = fmaf(ev.y, wv.y, acc);
    acc = fmaf(ev.z, wv.z, acc);
    acc = fmaf(ev.w, wv.w, acc);
  }
  pe[(size_t)v*128 + n] = acc;
}

// partial mean/max pools over S-chunks
__global__ __launch_bounds__(128) void k_pool(const int* __restrict__ x, const float* __restrict__ emb,
      float* __restrict__ psum, float* __restrict__ pmax)
{
  const int b = blockIdx.x, c = blockIdx.y, e = threadIdx.x;
  const int* xb = x + (size_t)b*S + c*(S/16);
  float s=0.f, m=-INFINITY;
  for (int k=0;k<S/16;++k){
    int v = xb[k];
    float val = emb[(size_t)v*E + e];
    s += val; m = fmaxf(m,val);
  }
  psum[((size_t)b*16 + c)*E + e] = s;
  pmax[((size_t)b*16 + c)*E + e] = m;
}

// layer-0 recurrence, fused gather: pre[t] = pe[x[t]] (pe is 409 KB -> L2-hot).
// Depth-4 ring for pe rows, depth-8 ring for x indices, hand-unrolled x8 so all
// ring slots are compile-time register indices (no scratch).
__global__ __launch_bounds__(64, 1) void k_rec0(const int* __restrict__ x,
                                                const float* __restrict__ pe,
                                                ushort_t* __restrict__ y,
                                                const float* __restrict__ w_hh,
                                                float* __restrict__ hfin)
{
  const int c = blockIdx.x;           // 0..255
  const int d = c >> 7;
  const int b = c & 127;
  const int i = threadIdx.x;          // 0..63
  float w[H];                         // stays in VGPRs (launch_bounds(64,1))
  const float* wrow = w_hh + ((size_t)d*H + i)*H;   // layer 0
  #pragma unroll
  for (int j=0;j<H;j+=4){
    float4 q = *(const float4*)(wrow+j);
    w[j]=q.x; w[j+1]=q.y; w[j+2]=q.z; w[j+3]=q.w;
  }
  const int* xb = x + (size_t)b*S;
  const float* peb = pe + d*H + i;    // + v*128 per step
  ushort_t* yb = y + (size_t)b*S*(2*H) + d*H + i;
  const int fwd = (d==0);
  const int dt = fwd ? 1 : -1;
  int t = fwd ? 0 : S-1;

  int vx[8];                          // x values for t .. t+7
  #pragma unroll
  for (int k=0;k<8;++k) vx[k] = xb[clamp_t(t + k*dt)];
  float pl[4];                        // pe rows for t .. t+3
  #pragma unroll
  for (int k=0;k<4;++k) pl[k] = peb[(size_t)vx[k]*128];
  float h = 0.f;

#define STEP0(r) do {                                                        \
    float acc = pl[(r)&3];                                                   \
    pl[(r)&3] = peb[(size_t)vx[((r)+4)&7]*128];  /* row for t+4 */           \
    vx[(r)&7] = xb[clamp_t(t + 8*dt)];           /* x for t+8  */            \
    float dotv; REC_DOT(dotv);                                               \
    acc += dotv;                                                             \
    h = fast_tanh(acc);                                                      \
    yb[(size_t)t*(2*H)] = f2bf(h);                                           \
    t += dt;                                                                 \
  } while(0)

  for (int tq=0; tq<S; tq+=8){
    STEP0(0); STEP0(1); STEP0(2); STEP0(3);
    STEP0(4); STEP0(5); STEP0(6); STEP0(7);
  }
#undef STEP0
  hfin[((size_t)d*B + b)*H + i] = h;
}

// layers 1,2 recurrence: pre streamed from HBM (134 MB, no L2 residency) ->
// depth-8 prefetch ring to cover ~900 cyc HBM latency (old depth gave 1 step).
__global__ __launch_bounds__(64, 1) void k_rec(const float* __restrict__ pre,
                                               ushort_t* __restrict__ y,
                                               const float* __restrict__ w_hh,
                                               float* __restrict__ hfin,
                                               int layer, int write_y)
{
  const int c = blockIdx.x;           // 0..255
  const int d = c >> 7;
  const int b = c & 127;
  const int i = threadIdx.x;          // 0..63
  float w[H];
  const float* wrow = w_hh + ((size_t)(layer*2+d)*H + i)*H;
  #pragma unroll
  for (int j=0;j<H;j+=4){
    float4 q = *(const float4*)(wrow+j);
    w[j]=q.x; w[j+1]=q.y; w[j+2]=q.z; w[j+3]=q.w;
  }
  const float* pb = pre + ((size_t)d*M + (size_t)b*S)*H + i;
  ushort_t* yb = y + (size_t)b*S*(2*H) + d*H + i;
  const int fwd = (d==0);
  const int dt = fwd ? 1 : -1;
  int t = fwd ? 0 : S-1;

  float pl[8];                        // pre values for t .. t+7
  #pragma unroll
  for (int k=0;k<8;++k) pl[k] = pb[(size_t)clamp_t(t + k*dt)*H];
  float h = 0.f;

#define STEPR(r) do {                                                        \
    float acc = pl[r];                                                       \
    pl[r] = pb[(size_t)clamp_t(t + 8*dt)*H];     /* value for t+8 */         \
    float dotv; REC_DOT(dotv);                                               \
    acc += dotv;                                                             \
    h = fast_tanh(acc);                                                      \
    if (write_y) yb[(size_t)t*(2*H)] = f2bf(h);                              \
    t += dt;                                                                 \
  } while(0)

  for (int tq=0; tq<S; tq+=8){
    STEPR(0); STEPR(1); STEPR(2); STEPR(3);
    STEPR(4); STEPR(5); STEPR(6); STEPR(7);
  }
#undef STEPR
  hfin[((size_t)d*B + b)*H + i] = h;
}

// layers 1,2 input projection: [M,128]@[128,128]^T. Yin is bf16, W is fp32.
#define KC 32
__global__ __launch_bounds__(256) void k_gemm(const ushort_t* __restrict__ Yin,
     const float* __restrict__ w_ih, const float* __restrict__ b_ih,
     const float* __restrict__ b_hh, float* __restrict__ pre, int layer)
{
  __shared__ float sY[KC][132];
  __shared__ float sW[KC][132];
  const int tid = threadIdx.x;
  const int m0 = blockIdx.x * 128;
  const int tn = (tid & 15) * 8;
  const int tm = (tid >> 4) * 8;
  float acc[8][8];
  #pragma unroll
  for (int a=0;a<8;++a)
    #pragma unroll
    for (int q=0;q<8;++q) acc[a][q]=0.f;
  const float* Wb = w_ih + (size_t)layer*2*H*E;
  for (int kc=0; kc<E; kc+=KC){
    #pragma unroll
    for (int r=0;r<2;++r){
      int idx = r*256 + tid;     // 0..511
      int ym = idx >> 2;         // 0..127
      int yk = (idx & 3)*8;      // 0,8,16,24
      const ushort_t* p = Yin + (size_t)(m0+ym)*E + kc + yk;
      ushort4 a = *(const ushort4*)p;
      ushort4 bq = *(const ushort4*)(p+4);
      sY[yk+0][ym]=bf2f(a.x);  sY[yk+1][ym]=bf2f(a.y);  sY[yk+2][ym]=bf2f(a.z);  sY[yk+3][ym]=bf2f(a.w);
      sY[yk+4][ym]=bf2f(bq.x); sY[yk+5][ym]=bf2f(bq.y); sY[yk+6][ym]=bf2f(bq.z); sY[yk+7][ym]=bf2f(bq.w);
    }
    #pragma unroll
    for (int r=0;r<4;++r){
      int idx = r*256 + tid;     // 0..1023
      int wn = idx >> 3;         // 0..127
      int wk = (idx & 7)*4;      // 0..28
      float4 v = *(const float4*)(Wb + (size_t)wn*E + kc + wk);
      sW[wk+0][wn]=v.x; sW[wk+1][wn]=v.y; sW[wk+2][wn]=v.z; sW[wk+3][wn]=v.w;
    }
    __syncthreads();
    #pragma unroll 4
    for (int k=0;k<KC;++k){
      float4 a0 = *(const float4*)&sY[k][tm];
      float4 a1 = *(const float4*)&sY[k][tm+4];
      float4 b0 = *(const float4*)&sW[k][tn];
      float4 b1 = *(const float4*)&sW[k][tn+4];
      float am[8]={a0.x,a0.y,a0.z,a0.w,a1.x,a1.y,a1.z,a1.w};
      float bn[8]={b0.x,b0.y,b0.z,b0.w,b1.x,b1.y,b1.z,b1.w};
      #pragma unroll
      for (int mi=0;mi<8;++mi)
        #pragma unroll
        for (int ni=0;ni<8;++ni)
          acc[mi][ni] = fmaf(am[mi], bn[ni], acc[mi][ni]);
    }
    __syncthreads();
  }
  const int d = tn >> 6;
  const int i0 = tn & 63;
  float bias[8];
  #pragma unroll
  for (int ni=0;ni<8;++ni)
    bias[ni] = b_ih[(size_t)(layer*2+d)*H + i0+ni] + b_hh[(size_t)(layer*2+d)*H + i0+ni];
  #pragma unroll
  for (int mi=0;mi<8;++mi){
    size_t off = ((size_t)d*M + (m0+tm+mi))*H + i0;
    float4 o0 = make_float4(acc[mi][0]+bias[0], acc[mi][1]+bias[1], acc[mi][2]+bias[2], acc[mi][3]+bias[3]);
    float4 o1 = make_float4(acc[mi][4]+bias[4], acc[mi][5]+bias[5], acc[mi][6]+bias[6], acc[mi][7]+bias[7]);
    *(float4*)(pre + off)     = o0;
    *(float4*)(pre + off + 4) = o1;
  }
}

// final FC head; also reduces the 16 pool partials. fp32 in/out.
__global__ __launch_bounds__(128) void k_fc(const float* __restrict__ psum, const float* __restrict__ pmax,
    const float* __restrict__ hfin, const float* __restrict__ fc1_w, const float* __restrict__ fc1_b,
    const float* __restrict__ fc2_w, const float* __restrict__ fc2_b, float* __restrict__ out)
{
  const int b = blockIdx.x, tid = threadIdx.x;
  __shared__ __align__(16) float comb[384];
  __shared__ float red[2];
  float s=0.f, m=-INFINITY;
  #pragma unroll
  for (int c=0;c<16;++c){
    s += psum[((size_t)b*16+c)*E + tid];
    m = fmaxf(m, pmax[((size_t)b*16+c)*E + tid]);
  }
  comb[128+tid] = s*(1.f/2048.f);
  comb[256+tid] = m;
  comb[tid] = (tid<64) ? hfin[(size_t)b*H + tid] : hfin[((size_t)B + b)*H + (tid-64)];
  __syncthreads();
  float acc = fc1_b[tid];
  const float4* wrow = (const float4*)(fc1_w + (size_t)tid*384);
  const float4* cb = (const float4*)comb;
  #pragma unroll 8
  for (int k=0;k<96;++k){
    float4 wv = wrow[k]; float4 cv = cb[k];
    acc = fmaf(wv.x,cv.x,acc); acc = fmaf(wv.y,cv.y,acc);
    acc = fmaf(wv.z,cv.z,acc); acc = fmaf(wv.w,cv.w,acc);
  }
  acc = fmaxf(acc, 0.f);
  float p = acc * fc2_w[tid];
  #pragma unroll
  for (int off=32; off>0; off>>=1) p += __shfl_down(p, off);
  if ((tid & 63)==0) red[tid>>6] = p;
  __syncthreads();
  if (tid==0) out[b] = red[0] + red[1] + fc2_b[0];
}

extern "C" void kernel_launch(void* const* d_in, const int* in_sizes, int n_in,
                              void* d_out, int out_size, void* d_ws, size_t ws_size,
                              hipStream_t stream)
{
  const int*   x     = (const int*)  d_in[0];
  const float* emb   = (const float*)d_in[1];
  const float* w_ih  = (const float*)d_in[2];
  const float* w_hh  = (const float*)d_in[3];
  const float* b_ih  = (const float*)d_in[4];
  const float* b_hh  = (const float*)d_in[5];
  const float* fc1_w = (const float*)d_in[6];
  const float* fc1_b = (const float*)d_in[7];
  const float* fc2_w = (const float*)d_in[8];
  const float* fc2_b = (const float*)d_in[9];
  float* out = (float*)d_out;

  // workspace: keep under ~204 MB
  char* ws = (char*)d_ws;
  float*    pre  = (float*)(ws);                                     // 2*M*H f32  = 134.2 MB (layers 1,2 only)
  ushort_t* y    = (ushort_t*)(ws + (size_t)2*M*H*4);                // M*128 bf16 =  67.1 MB
  float*    pe   = (float*)(ws + (size_t)2*M*H*4 + (size_t)M*128*2); // V*128 f32
  float*    psum = pe   + (size_t)V*128;                             // B*16*E f32
  float*    pmax = psum + (size_t)B*16*E;                            // B*16*E f32
  float*    hfin = pmax + (size_t)B*16*E;                            // 2*B*H f32

  k_pre_emb<<<V, 128, 0, stream>>>(emb, w_ih, b_ih, b_hh, pe);
  k_pool<<<dim3(B,16), 128, 0, stream>>>(x, emb, psum, pmax);
  k_rec0<<<256, 64, 0, stream>>>(x, pe, y, w_hh, hfin);
  k_gemm<<<M/128, 256, 0, stream>>>(y, w_ih, b_ih, b_hh, pre, 1);
  k_rec<<<256, 64, 0, stream>>>(pre, y, w_hh, hfin, 1, 1);
  k_gemm<<<M/128, 256, 0, stream>>>(y, w_ih, b_ih, b_hh, pre, 2);
  k_rec<<<256, 64, 0, stream>>>(pre, y, w_hh, hfin, 2, 0);
  k_fc<<<B, 128, 0, stream>>>(psum, pmax, hfin, fc1_w, fc1_b, fc2_w, fc2_b, out);
}

// Round 2
// 1760.408 us; speedup vs baseline: 1.1696x; 1.1696x over previous
//
#include <hip/hip_runtime.h>
#include <math.h>

#define B 128
#define S 2048
#define V 800
#define E 128
#define H 64
#define NL 3
#define M (B*S)

typedef unsigned short ushort_t;
typedef float f32x2 __attribute__((ext_vector_type(2)));
typedef float f32x4 __attribute__((ext_vector_type(4)));

__device__ __forceinline__ float bf2f(unsigned short u){
  return __uint_as_float(((unsigned int)u) << 16);
}
__device__ __forceinline__ unsigned short f2bf(float f){
  unsigned int u = __float_as_uint(f);
  u += 0x7fff + ((u >> 16) & 1);          // round-to-nearest-even
  return (unsigned short)(u >> 16);
}
__device__ __forceinline__ float fast_tanh(float x){
  float e = __expf(2.f*x);
  return 1.f - 2.f*__builtin_amdgcn_rcpf(e+1.f);
}
__device__ __forceinline__ int clamp_t(int t){
  return t < 0 ? 0 : (t > S-1 ? S-1 : t);
}
// packed dual-f32 FMA: acc.lo += a.lo*b.lo; acc.hi += a.hi*b.hi
__device__ __forceinline__ void pk_fma(f32x2& acc, f32x2 a, f32x2 b){
  asm("v_pk_fma_f32 %0, %1, %2, %0" : "+v"(acc) : "v"(a), "v"(b));
}

// 64-term dot of wave-distributed h (lane i owns h[i]) against per-lane row w2[32].
// h broadcast via LDS: 1 ds_write_b32 + 16 uniform-address ds_read_b128 (free
// broadcast, no bank conflicts) instead of 64 v_readlane. 32 v_pk_fma_f32
// instead of 64 v_fma_f32. Single wave/block -> in-order DS pipe, no barrier.
#define REC_DOT_LDS(dotv) do {                                               \
  hsh[i] = h;                                                                \
  __builtin_amdgcn_wave_barrier();                                           \
  f32x2 a0_={0.f,0.f},a1_={0.f,0.f},a2_={0.f,0.f},a3_={0.f,0.f};             \
  _Pragma("unroll")                                                          \
  for (int q=0;q<16;q+=4){                                                   \
    f32x4 b0_ = hb[q+0], b1_ = hb[q+1], b2_ = hb[q+2], b3_ = hb[q+3];        \
    pk_fma(a0_, w2[2*q+0], b0_.xy); pk_fma(a1_, w2[2*q+1], b0_.zw);          \
    pk_fma(a2_, w2[2*q+2], b1_.xy); pk_fma(a3_, w2[2*q+3], b1_.zw);          \
    pk_fma(a0_, w2[2*q+4], b2_.xy); pk_fma(a1_, w2[2*q+5], b2_.zw);          \
    pk_fma(a2_, w2[2*q+6], b3_.xy); pk_fma(a3_, w2[2*q+7], b3_.zw);          \
  }                                                                          \
  dotv = ((a0_.x+a0_.y)+(a1_.x+a1_.y))+((a2_.x+a2_.y)+(a3_.x+a3_.y));        \
} while(0)

// pre_emb[v][n] = emb[v]·w_ih[0,n,:] + b_ih[0,n] + b_hh[0,n],  n = d*64+i
__global__ __launch_bounds__(128) void k_pre_emb(const float* __restrict__ emb,
    const float* __restrict__ w_ih, const float* __restrict__ b_ih, const float* __restrict__ b_hh,
    float* __restrict__ pe)
{
  const int v = blockIdx.x;
  const int n = threadIdx.x;           // 0..127
  const float* er = emb + (size_t)v*E;
  const float* wr = w_ih + (size_t)n*E;   // layer 0 rows
  float acc = b_ih[n] + b_hh[n];
  #pragma unroll
  for (int e=0;e<E;e+=4){
    float4 ev = *(const float4*)(er+e);
    float4 wv = *(const float4*)(wr+e);
    acc = fmaf(ev.x, wv.x, acc);
    acc = fmaf(ev.y, wv.y, acc);
    acc = fmaf(ev.z, wv.z, acc);
    acc = fmaf(ev.w, wv.w, acc);
  }
  pe[(size_t)v*128 + n] = acc;
}

// partial mean/max pools over S-chunks
__global__ __launch_bounds__(128) void k_pool(const int* __restrict__ x, const float* __restrict__ emb,
      float* __restrict__ psum, float* __restrict__ pmax)
{
  const int b = blockIdx.x, c = blockIdx.y, e = threadIdx.x;
  const int* xb = x + (size_t)b*S + c*(S/16);
  float s=0.f, m=-INFINITY;
  for (int k=0;k<S/16;++k){
    int v = xb[k];
    float val = emb[(size_t)v*E + e];
    s += val; m = fmaxf(m,val);
  }
  psum[((size_t)b*16 + c)*E + e] = s;
  pmax[((size_t)b*16 + c)*E + e] = m;
}

// layer-0 recurrence, fused gather: pre[t] = pe[x[t]] (pe is 409 KB -> L2-hot).
__global__ __attribute__((amdgpu_flat_work_group_size(64,64)))
__attribute__((amdgpu_waves_per_eu(1,1)))
void k_rec0(const int* __restrict__ x,
            const float* __restrict__ pe,
            ushort_t* __restrict__ y,
            const float* __restrict__ w_hh,
            float* __restrict__ hfin)
{
  __shared__ __align__(16) float hsh[64];
  const f32x4* hb = (const f32x4*)hsh;
  const int c = blockIdx.x;           // 0..255
  const int d = c >> 7;
  const int b = c & 127;
  const int i = threadIdx.x;          // 0..63
  f32x2 w2[32];                       // 64 weights resident in VGPR pairs
  const float* wrow = w_hh + ((size_t)d*H + i)*H;   // layer 0
  #pragma unroll
  for (int j=0;j<H;j+=4){
    float4 q = *(const float4*)(wrow+j);
    w2[j/2]   = (f32x2){q.x, q.y};
    w2[j/2+1] = (f32x2){q.z, q.w};
  }
  const int* xb = x + (size_t)b*S;
  const float* peb = pe + d*H + i;    // + v*128 per step
  ushort_t* yb = y + (size_t)b*S*(2*H) + d*H + i;
  const int fwd = (d==0);
  const int dt = fwd ? 1 : -1;
  int t = fwd ? 0 : S-1;

  int vx[8];                          // x values for t .. t+7
  #pragma unroll
  for (int k=0;k<8;++k) vx[k] = xb[clamp_t(t + k*dt)];
  float pl[4];                        // pe rows for t .. t+3
  #pragma unroll
  for (int k=0;k<4;++k) pl[k] = peb[(size_t)vx[k]*128];
  float h = 0.f;

#define STEP0(r) do {                                                        \
    float acc = pl[(r)&3];                                                   \
    pl[(r)&3] = peb[(size_t)vx[((r)+4)&7]*128];  /* row for t+4 */           \
    vx[(r)&7] = xb[clamp_t(t + 8*dt)];           /* x for t+8  */            \
    float dotv; REC_DOT_LDS(dotv);                                           \
    acc += dotv;                                                             \
    h = fast_tanh(acc);                                                      \
    yb[(size_t)t*(2*H)] = f2bf(h);                                           \
    t += dt;                                                                 \
  } while(0)

  for (int tq=0; tq<S; tq+=8){
    STEP0(0); STEP0(1); STEP0(2); STEP0(3);
    STEP0(4); STEP0(5); STEP0(6); STEP0(7);
  }
#undef STEP0
  hfin[((size_t)d*B + b)*H + i] = h;
}

// layers 1,2 recurrence: pre streamed from HBM (134 MB), depth-8 prefetch ring.
__global__ __attribute__((amdgpu_flat_work_group_size(64,64)))
__attribute__((amdgpu_waves_per_eu(1,1)))
void k_rec(const float* __restrict__ pre,
           ushort_t* __restrict__ y,
           const float* __restrict__ w_hh,
           float* __restrict__ hfin,
           int layer, int write_y)
{
  __shared__ __align__(16) float hsh[64];
  const f32x4* hb = (const f32x4*)hsh;
  const int c = blockIdx.x;           // 0..255
  const int d = c >> 7;
  const int b = c & 127;
  const int i = threadIdx.x;          // 0..63
  f32x2 w2[32];
  const float* wrow = w_hh + ((size_t)(layer*2+d)*H + i)*H;
  #pragma unroll
  for (int j=0;j<H;j+=4){
    float4 q = *(const float4*)(wrow+j);
    w2[j/2]   = (f32x2){q.x, q.y};
    w2[j/2+1] = (f32x2){q.z, q.w};
  }
  const float* pb = pre + ((size_t)d*M + (size_t)b*S)*H + i;
  ushort_t* yb = y + (size_t)b*S*(2*H) + d*H + i;
  const int fwd = (d==0);
  const int dt = fwd ? 1 : -1;
  int t = fwd ? 0 : S-1;

  float pl[8];                        // pre values for t .. t+7
  #pragma unroll
  for (int k=0;k<8;++k) pl[k] = pb[(size_t)clamp_t(t + k*dt)*H];
  float h = 0.f;

#define STEPR(r) do {                                                        \
    float acc = pl[r];                                                       \
    pl[r] = pb[(size_t)clamp_t(t + 8*dt)*H];     /* value for t+8 */         \
    float dotv; REC_DOT_LDS(dotv);                                           \
    acc += dotv;                                                             \
    h = fast_tanh(acc);                                                      \
    if (write_y) yb[(size_t)t*(2*H)] = f2bf(h);                              \
    t += dt;                                                                 \
  } while(0)

  for (int tq=0; tq<S; tq+=8){
    STEPR(0); STEPR(1); STEPR(2); STEPR(3);
    STEPR(4); STEPR(5); STEPR(6); STEPR(7);
  }
#undef STEPR
  hfin[((size_t)d*B + b)*H + i] = h;
}

// layers 1,2 input projection: [M,128]@[128,128]^T. Yin is bf16, W is fp32.
#define KC 32
__global__ __launch_bounds__(256) void k_gemm(const ushort_t* __restrict__ Yin,
     const float* __restrict__ w_ih, const float* __restrict__ b_ih,
     const float* __restrict__ b_hh, float* __restrict__ pre, int layer)
{
  __shared__ float sY[KC][132];
  __shared__ float sW[KC][132];
  const int tid = threadIdx.x;
  const int m0 = blockIdx.x * 128;
  const int tn = (tid & 15) * 8;
  const int tm = (tid >> 4) * 8;
  float acc[8][8];
  #pragma unroll
  for (int a=0;a<8;++a)
    #pragma unroll
    for (int q=0;q<8;++q) acc[a][q]=0.f;
  const float* Wb = w_ih + (size_t)layer*2*H*E;
  for (int kc=0; kc<E; kc+=KC){
    #pragma unroll
    for (int r=0;r<2;++r){
      int idx = r*256 + tid;     // 0..511
      int ym = idx >> 2;         // 0..127
      int yk = (idx & 3)*8;      // 0,8,16,24
      const ushort_t* p = Yin + (size_t)(m0+ym)*E + kc + yk;
      ushort4 a = *(const ushort4*)p;
      ushort4 bq = *(const ushort4*)(p+4);
      sY[yk+0][ym]=bf2f(a.x);  sY[yk+1][ym]=bf2f(a.y);  sY[yk+2][ym]=bf2f(a.z);  sY[yk+3][ym]=bf2f(a.w);
      sY[yk+4][ym]=bf2f(bq.x); sY[yk+5][ym]=bf2f(bq.y); sY[yk+6][ym]=bf2f(bq.z); sY[yk+7][ym]=bf2f(bq.w);
    }
    #pragma unroll
    for (int r=0;r<4;++r){
      int idx = r*256 + tid;     // 0..1023
      int wn = idx >> 3;         // 0..127
      int wk = (idx & 7)*4;      // 0..28
      float4 v = *(const float4*)(Wb + (size_t)wn*E + kc + wk);
      sW[wk+0][wn]=v.x; sW[wk+1][wn]=v.y; sW[wk+2][wn]=v.z; sW[wk+3][wn]=v.w;
    }
    __syncthreads();
    #pragma unroll 4
    for (int k=0;k<KC;++k){
      float4 a0 = *(const float4*)&sY[k][tm];
      float4 a1 = *(const float4*)&sY[k][tm+4];
      float4 b0 = *(const float4*)&sW[k][tn];
      float4 b1 = *(const float4*)&sW[k][tn+4];
      float am[8]={a0.x,a0.y,a0.z,a0.w,a1.x,a1.y,a1.z,a1.w};
      float bn[8]={b0.x,b0.y,b0.z,b0.w,b1.x,b1.y,b1.z,b1.w};
      #pragma unroll
      for (int mi=0;mi<8;++mi)
        #pragma unroll
        for (int ni=0;ni<8;++ni)
          acc[mi][ni] = fmaf(am[mi], bn[ni], acc[mi][ni]);
    }
    __syncthreads();
  }
  const int d = tn >> 6;
  const int i0 = tn & 63;
  float bias[8];
  #pragma unroll
  for (int ni=0;ni<8;++ni)
    bias[ni] = b_ih[(size_t)(layer*2+d)*H + i0+ni] + b_hh[(size_t)(layer*2+d)*H + i0+ni];
  #pragma unroll
  for (int mi=0;mi<8;++mi){
    size_t off = ((size_t)d*M + (m0+tm+mi))*H + i0;
    float4 o0 = make_float4(acc[mi][0]+bias[0], acc[mi][1]+bias[1], acc[mi][2]+bias[2], acc[mi][3]+bias[3]);
    float4 o1 = make_float4(acc[mi][4]+bias[4], acc[mi][5]+bias[5], acc[mi][6]+bias[6], acc[mi][7]+bias[7]);
    *(float4*)(pre + off)     = o0;
    *(float4*)(pre + off + 4) = o1;
  }
}

// final FC head; also reduces the 16 pool partials. fp32 in/out.
__global__ __launch_bounds__(128) void k_fc(const float* __restrict__ psum, const float* __restrict__ pmax,
    const float* __restrict__ hfin, const float* __restrict__ fc1_w, const float* __restrict__ fc1_b,
    const float* __restrict__ fc2_w, const float* __restrict__ fc2_b, float* __restrict__ out)
{
  const int b = blockIdx.x, tid = threadIdx.x;
  __shared__ __align__(16) float comb[384];
  __shared__ float red[2];
  float s=0.f, m=-INFINITY;
  #pragma unroll
  for (int c=0;c<16;++c){
    s += psum[((size_t)b*16+c)*E + tid];
    m = fmaxf(m, pmax[((size_t)b*16+c)*E + tid]);
  }
  comb[128+tid] = s*(1.f/2048.f);
  comb[256+tid] = m;
  comb[tid] = (tid<64) ? hfin[(size_t)b*H + tid] : hfin[((size_t)B + b)*H + (tid-64)];
  __syncthreads();
  float acc = fc1_b[tid];
  const float4* wrow = (const float4*)(fc1_w + (size_t)tid*384);
  const float4* cb = (const float4*)comb;
  #pragma unroll 8
  for (int k=0;k<96;++k){
    float4 wv = wrow[k]; float4 cv = cb[k];
    acc = fmaf(wv.x,cv.x,acc); acc = fmaf(wv.y,cv.y,acc);
    acc = fmaf(wv.z,cv.z,acc); acc = fmaf(wv.w,cv.w,acc);
  }
  acc = fmaxf(acc, 0.f);
  float p = acc * fc2_w[tid];
  #pragma unroll
  for (int off=32; off>0; off>>=1) p += __shfl_down(p, off);
  if ((tid & 63)==0) red[tid>>6] = p;
  __syncthreads();
  if (tid==0) out[b] = red[0] + red[1] + fc2_b[0];
}

extern "C" void kernel_launch(void* const* d_in, const int* in_sizes, int n_in,
                              void* d_out, int out_size, void* d_ws, size_t ws_size,
                              hipStream_t stream)
{
  const int*   x     = (const int*)  d_in[0];
  const float* emb   = (const float*)d_in[1];
  const float* w_ih  = (const float*)d_in[2];
  const float* w_hh  = (const float*)d_in[3];
  const float* b_ih  = (const float*)d_in[4];
  const float* b_hh  = (const float*)d_in[5];
  const float* fc1_w = (const float*)d_in[6];
  const float* fc1_b = (const float*)d_in[7];
  const float* fc2_w = (const float*)d_in[8];
  const float* fc2_b = (const float*)d_in[9];
  float* out = (float*)d_out;

  // workspace: keep under ~204 MB
  char* ws = (char*)d_ws;
  float*    pre  = (float*)(ws);                                     // 2*M*H f32  = 134.2 MB (layers 1,2 only)
  ushort_t* y    = (ushort_t*)(ws + (size_t)2*M*H*4);                // M*128 bf16 =  67.1 MB
  float*    pe   = (float*)(ws + (size_t)2*M*H*4 + (size_t)M*128*2); // V*128 f32
  float*    psum = pe   + (size_t)V*128;                             // B*16*E f32
  float*    pmax = psum + (size_t)B*16*E;                            // B*16*E f32
  float*    hfin = pmax + (size_t)B*16*E;                            // 2*B*H f32

  k_pre_emb<<<V, 128, 0, stream>>>(emb, w_ih, b_ih, b_hh, pe);
  k_pool<<<dim3(B,16), 128, 0, stream>>>(x, emb, psum, pmax);
  k_rec0<<<256, 64, 0, stream>>>(x, pe, y, w_hh, hfin);
  k_gemm<<<M/128, 256, 0, stream>>>(y, w_ih, b_ih, b_hh, pre, 1);
  k_rec<<<256, 64, 0, stream>>>(pre, y, w_hh, hfin, 1, 1);
  k_gemm<<<M/128, 256, 0, stream>>>(y, w_ih, b_ih, b_hh, pre, 2);
  k_rec<<<256, 64, 0, stream>>>(pre, y, w_hh, hfin, 2, 0);
  k_fc<<<B, 128, 0, stream>>>(psum, pmax, hfin, fc1_w, fc1_b, fc2_w, fc2_b, out);
}